// Round 6
// baseline (1322.661 us; speedup 1.0000x reference)
//
#include <hip/hip_runtime.h>
#include <hip/hip_bf16.h>
#include <stdint.h>

typedef __attribute__((ext_vector_type(8))) short short8;
typedef __attribute__((ext_vector_type(4))) float f32x4;
typedef unsigned long long u64;

#define DI static __device__ __forceinline__

DI unsigned short f2b(float f){
  unsigned u = __float_as_uint(f);
  u = (u + 0x7FFFu + ((u >> 16) & 1u)) >> 16;
  return (unsigned short)u;
}
DI float sigm(float x){ return 1.0f / (1.0f + __expf(-x)); }
DI float tanh_(float x){ return 1.0f - 2.0f / (__expf(2.0f*x) + 1.0f); } // safe at +/-inf

// ---- embedding gather: Xbf[r' = t*64+b][256] = bf16(emb[input[b][t]])
__global__ void k_gather(const int* __restrict__ inp, const float* __restrict__ emb,
                         unsigned short* __restrict__ Xbf){
  int r = blockIdx.x;            // r' = t*64 + b
  int t = r >> 6, b = r & 63;
  int idx = inp[b*128 + t];
  float v = emb[(size_t)idx*256 + threadIdx.x];
  Xbf[(size_t)r*256 + threadIdx.x] = f2b(v);
}

// ---- transpose src[R][C] (rows row0..row0+R-1, ld) -> dst[C][R] bf16
__global__ void k_transpose(const float* __restrict__ src, unsigned short* __restrict__ dst,
                            int R, int C, int ld, int row0){
  __shared__ float tile[32][33];
  int tx = threadIdx.x, ty = threadIdx.y;
  int x = blockIdx.x*32 + tx;
  for (int i = 0; i < 4; i++){
    int y = blockIdx.y*32 + ty + i*8;
    if (x < C && y < R) tile[ty + i*8][tx] = src[(size_t)(row0 + y)*ld + x];
  }
  __syncthreads();
  int y2 = blockIdx.y*32 + tx;                 // R index
  for (int i = 0; i < 4; i++){
    int x2 = blockIdx.x*32 + ty + i*8;         // C index
    if (x2 < C && y2 < R) dst[(size_t)x2*R + y2] = f2b(tile[tx][ty + i*8]);
  }
}

// ---- MFMA GEMM (m97 pattern): C[m][n] = sum_k A[m][k]*Bt[n][k], A/Bt bf16 [rows][256]
// m0 = blockIdx.x (fast) so consecutive blocks share the same B-tile (L2 reuse).
// EPI 0: Z0x store (+bias b0), rows r'=(t,b) -> Z0x[t][n][b]
// EPI 1: fused softmax partial: S[row] += sum exp(logit+bias); LT[row] = logit_tgt
template<int EPI>
__launch_bounds__(256, 2)
__global__ void k_gemm(const unsigned short* __restrict__ A, const unsigned short* __restrict__ Bt,
                       float* __restrict__ outZ, const float* __restrict__ bias,
                       const int* __restrict__ tgt, float* __restrict__ S, float* __restrict__ LT){
  __shared__ unsigned short As[128*64];
  __shared__ unsigned short Bs[128*64];
  __shared__ int tgt_s[128];
  const int m0 = blockIdx.x*128, n0 = blockIdx.y*128;
  const int tid = threadIdx.x;
  const int w = tid >> 6, l = tid & 63;
  const int quad = l >> 4, l15 = l & 15;
  const int wm = (w >> 1)*64, wn = (w & 1)*64;
  const int lrow = l >> 3, ls = l & 7;         // lane -> (row-in-group, slot)
  f32x4 acc[4][4] = {};
  if (EPI == 1 && tid < 128) tgt_s[tid] = tgt[m0 + tid];

  for (int k0 = 0; k0 < 256; k0 += 64){
    #pragma unroll
    for (int it = 0; it < 4; it++){
      int row = it*32 + w*8 + lrow;
      int csrc = ls ^ (row & 7);               // XOR swizzle: slot s holds chunk s^(row&7)
      __builtin_amdgcn_global_load_lds(
        (const __attribute__((address_space(1))) unsigned*)&A[(size_t)(m0+row)*256 + k0 + csrc*8],
        (__attribute__((address_space(3))) unsigned*)&As[(it*32 + w*8)*64], 16, 0, 0);
      __builtin_amdgcn_global_load_lds(
        (const __attribute__((address_space(1))) unsigned*)&Bt[(size_t)(n0+row)*256 + k0 + csrc*8],
        (__attribute__((address_space(3))) unsigned*)&Bs[(it*32 + w*8)*64], 16, 0, 0);
    }
    __syncthreads();
    #pragma unroll
    for (int ks = 0; ks < 64; ks += 32){
      const int cki = (ks >> 3) + quad;        // k-chunk index 0..7
      short8 af[4], bfr[4];
      #pragma unroll
      for (int i = 0; i < 4; i++){
        int row = wm + i*16 + l15;
        af[i]  = *(short8*)&As[row*64 + (cki ^ (row & 7))*8];
      }
      #pragma unroll
      for (int j = 0; j < 4; j++){
        int row = wn + j*16 + l15;
        bfr[j] = *(short8*)&Bs[row*64 + (cki ^ (row & 7))*8];
      }
      #pragma unroll
      for (int i = 0; i < 4; i++)
        #pragma unroll
        for (int j = 0; j < 4; j++)
          acc[i][j] = __builtin_amdgcn_mfma_f32_16x16x32_bf16(af[i], bfr[j], acc[i][j], 0, 0, 0);
    }
    __syncthreads();
  }

  if (EPI == 0){
    #pragma unroll
    for (int i = 0; i < 4; i++){
      int mg = m0 + wm + i*16 + quad*4;        // rows mg..mg+3 in this reg quad
      int t = mg >> 6, b = mg & 63;
      #pragma unroll
      for (int j = 0; j < 4; j++){
        int ng = n0 + wn + j*16 + l15;
        float bb = bias[ng];
        f32x4 v = acc[i][j];
        v[0] += bb; v[1] += bb; v[2] += bb; v[3] += bb;
        *(f32x4*)&outZ[((size_t)t*1024 + ng)*64 + b] = v;
      }
    }
  } else {
    #pragma unroll
    for (int i = 0; i < 4; i++){
      float rs[4] = {0.f,0.f,0.f,0.f};
      #pragma unroll
      for (int j = 0; j < 4; j++){
        int ng = n0 + wn + j*16 + l15;
        float bb = bias[ng];
        f32x4 v = acc[i][j];
        #pragma unroll
        for (int r = 0; r < 4; r++){
          float e = v[r] + bb;
          int mloc = wm + i*16 + quad*4 + r;
          if (tgt_s[mloc] == ng) LT[m0 + mloc] = e;
          rs[r] += __expf(e);
        }
      }
      #pragma unroll
      for (int r = 0; r < 4; r++){
        float s = rs[r];
        s += __shfl_xor(s, 1, 16);
        s += __shfl_xor(s, 2, 16);
        s += __shfl_xor(s, 4, 16);
        s += __shfl_xor(s, 8, 16);
        if (l15 == 0) atomicAdd(&S[m0 + wm + i*16 + quad*4 + r], s);
      }
    }
  }
}

// ---- wave-level canary poll: each lane checks word (l & 15); exit when all 16 == expv.
DI void pollw(const unsigned* cz, int l, unsigned expv){
  for(;;){
    unsigned v = __hip_atomic_load(cz + (l & 15), __ATOMIC_RELAXED, __HIP_MEMORY_SCOPE_AGENT);
    if (__ballot(v == expv) == ~0ull) break;
    __builtin_amdgcn_s_sleep(1);
  }
  asm volatile("" ::: "memory");
}
DI void st_short_llc(unsigned short* p, unsigned v){
  asm volatile("global_store_short %0, %1, off sc0 sc1" :: "v"(p), "v"(v) : "memory");
}

// ---- persistent 2-layer LSTM, 8 WGs x 256 cooperative.
// WG 0..3: layer0, WG 4..7: layer1; each wave owns 16 units (64 gate-cols, gates = j-tiles
// g*256+u -> all 4 gates of a unit land in ONE lane's acc regs: register-local cell update).
// h exchange: [kb=u/8][b][u%8] bf16 chunks in full-history buffers; producers publish with
// scalar sc0sc1 stores + vmcnt(0) + per-wave canary word; consumers ballot-poll canaries
// then bulk-stage via global_load_lds (fresh addresses each t -> plain cached path safe).
__launch_bounds__(256, 1)
__global__ void k_lstm(const float* __restrict__ Z0x,          // [128 t][1024 n][64 b] f32 (b0 folded)
                       const unsigned short* __restrict__ W0h, // [1024 n][256 k] bf16
                       const unsigned short* __restrict__ W1,  // [1024 n][512 k] bf16
                       const float* __restrict__ b1,
                       unsigned short* __restrict__ h0h,       // [128 t][32 kb][64 b][8]
                       unsigned short* __restrict__ h1h,       // [128 t][32 kb][64 b][8]
                       unsigned short* __restrict__ H1bf,      // [b*128+t][256 u]
                       unsigned* __restrict__ canary0,         // [128][16]
                       unsigned* __restrict__ canary1){        // [128][16]
  __shared__ __align__(16) char smraw[65536];
  unsigned short* hs0 = (unsigned short*)smraw;            // 32 KB: h0 frags
  unsigned short* hs1 = (unsigned short*)(smraw + 32768);  // 32 KB: h1 frags (L1 only)

  const int wg = blockIdx.x;
  const bool L0 = (wg < 4);
  const int tid = threadIdx.x;
  const int w = tid >> 6, l = tid & 63, quad = l >> 4, l15 = l & 15;

  float c_st[16];
  #pragma unroll
  for (int i = 0; i < 16; i++) c_st[i] = 0.f;

  if (L0){
    const int gw = wg*4 + w;                   // [0,16)
    const int u0 = gw*16;
    short8 bw[32];                             // [g][ks] 128 VGPR
    #pragma unroll
    for (int g = 0; g < 4; g++)
      #pragma unroll
      for (int ks = 0; ks < 8; ks++)
        bw[g*8+ks] = *(const short8*)&W0h[(size_t)(g*256 + u0 + l15)*256 + ks*32 + quad*8];

    for (int t = 0; t < 128; t++){
      f32x4 acc[4][4];
      #pragma unroll
      for (int i = 0; i < 4; i++)
        #pragma unroll
        for (int g = 0; g < 4; g++)
          acc[i][g] = *(const f32x4*)&Z0x[((size_t)t*1024 + g*256 + u0 + l15)*64 + i*16 + quad*4];
      if (t > 0){
        __syncthreads();                       // B1: siblings done reading hs0 of t-1
        pollw(canary0 + (t-1)*16, l, (unsigned)t);
        #pragma unroll
        for (int it = 0; it < 8; it++){
          int c = it*256 + w*64 + l;
          __builtin_amdgcn_global_load_lds(
            (const __attribute__((address_space(1))) unsigned*)&h0h[((size_t)(t-1)*2048 + c)*8],
            (__attribute__((address_space(3))) unsigned*)&hs0[(size_t)(it*256 + w*64)*8], 16, 0, 0);
        }
        __syncthreads();                       // B2: staged (drains vmcnt)
        #pragma unroll
        for (int ks = 0; ks < 8; ks++){
          short8 a[4];
          #pragma unroll
          for (int i = 0; i < 4; i++)
            a[i] = *(const short8*)&hs0[(((ks*4+quad)*64) + i*16 + l15)*8];
          #pragma unroll
          for (int i = 0; i < 4; i++)
            #pragma unroll
            for (int g = 0; g < 4; g++)
              acc[i][g] = __builtin_amdgcn_mfma_f32_16x16x32_bf16(a[i], bw[g*8+ks], acc[i][g], 0, 0, 0);
        }
      }
      // register-local cell update: this lane = unit u0+l15, 16 batches
      const int kb = (u0 >> 3) + (l15 >> 3), pos = l15 & 7;
      #pragma unroll
      for (int i = 0; i < 4; i++)
        #pragma unroll
        for (int r = 0; r < 4; r++){
          float zi = acc[i][0][r], zj = acc[i][1][r], zf = acc[i][2][r], zo = acc[i][3][r];
          float c = c_st[i*4+r]*sigm(zf + 1.0f) + sigm(zi)*tanh_(zj);
          c_st[i*4+r] = c;
          unsigned short hv = f2b(tanh_(c)*sigm(zo));
          int b = i*16 + quad*4 + r;
          st_short_llc(h0h + ((size_t)t*2048 + (size_t)kb*64 + b)*8 + pos, (unsigned)hv);
        }
      asm volatile("s_waitcnt vmcnt(0)" ::: "memory");
      if (l == 0)
        __hip_atomic_store(canary0 + t*16 + gw, (unsigned)(t+1), __ATOMIC_RELAXED, __HIP_MEMORY_SCOPE_AGENT);
    }
  } else {
    const int gw = (wg-4)*4 + w;               // [0,16)
    const int u0 = gw*16;
    short8 bw[64];                             // [g][ks] 256 VGPR
    #pragma unroll
    for (int g = 0; g < 4; g++)
      #pragma unroll
      for (int ks = 0; ks < 16; ks++)
        bw[g*16+ks] = *(const short8*)&W1[(size_t)(g*256 + u0 + l15)*512 + ks*32 + quad*8];
    float b1r[4];
    #pragma unroll
    for (int g = 0; g < 4; g++) b1r[g] = b1[g*256 + u0 + l15];

    for (int t = 0; t < 128; t++){
      f32x4 acc[4][4] = {};
      if (t > 0){
        __syncthreads();                       // B1: siblings done reading hs0/hs1 of t-1
        pollw(canary1 + (t-1)*16, l, (unsigned)t);
        #pragma unroll
        for (int it = 0; it < 8; it++){
          int c = it*256 + w*64 + l;
          __builtin_amdgcn_global_load_lds(
            (const __attribute__((address_space(1))) unsigned*)&h1h[((size_t)(t-1)*2048 + c)*8],
            (__attribute__((address_space(3))) unsigned*)&hs1[(size_t)(it*256 + w*64)*8], 16, 0, 0);
        }
        __syncthreads();                       // B2: h1 staged
        #pragma unroll
        for (int ks = 8; ks < 16; ks++){       // h1 half (k 256..511)
          short8 a[4];
          #pragma unroll
          for (int i = 0; i < 4; i++)
            a[i] = *(const short8*)&hs1[((((ks-8)*4+quad)*64) + i*16 + l15)*8];
          #pragma unroll
          for (int i = 0; i < 4; i++)
            #pragma unroll
            for (int g = 0; g < 4; g++)
              acc[i][g] = __builtin_amdgcn_mfma_f32_16x16x32_bf16(a[i], bw[g*16+ks], acc[i][g], 0, 0, 0);
        }
      }
      // critical h0(t)
      pollw(canary0 + t*16, l, (unsigned)(t+1));
      #pragma unroll
      for (int it = 0; it < 8; it++){
        int c = it*256 + w*64 + l;
        __builtin_amdgcn_global_load_lds(
          (const __attribute__((address_space(1))) unsigned*)&h0h[((size_t)t*2048 + c)*8],
          (__attribute__((address_space(3))) unsigned*)&hs0[(size_t)(it*256 + w*64)*8], 16, 0, 0);
      }
      __syncthreads();                         // B3: h0 staged
      #pragma unroll
      for (int ks = 0; ks < 8; ks++){
        short8 a[4];
        #pragma unroll
        for (int i = 0; i < 4; i++)
          a[i] = *(const short8*)&hs0[(((ks*4+quad)*64) + i*16 + l15)*8];
        #pragma unroll
        for (int i = 0; i < 4; i++)
          #pragma unroll
          for (int g = 0; g < 4; g++)
            acc[i][g] = __builtin_amdgcn_mfma_f32_16x16x32_bf16(a[i], bw[g*16+ks], acc[i][g], 0, 0, 0);
      }
      // register-local cell update
      const int kb = (u0 >> 3) + (l15 >> 3), pos = l15 & 7;
      #pragma unroll
      for (int i = 0; i < 4; i++)
        #pragma unroll
        for (int r = 0; r < 4; r++){
          float zi = acc[i][0][r] + b1r[0], zj = acc[i][1][r] + b1r[1];
          float zf = acc[i][2][r] + b1r[2], zo = acc[i][3][r] + b1r[3];
          float c = c_st[i*4+r]*sigm(zf + 1.0f) + sigm(zi)*tanh_(zj);
          c_st[i*4+r] = c;
          unsigned short hv = f2b(tanh_(c)*sigm(zo));
          int b = i*16 + quad*4 + r;
          st_short_llc(h1h + ((size_t)t*2048 + (size_t)kb*64 + b)*8 + pos, (unsigned)hv);
          H1bf[((size_t)b*128 + t)*256 + u0 + l15] = hv;   // plain cached store
        }
      asm volatile("s_waitcnt vmcnt(0)" ::: "memory");
      if (l == 0)
        __hip_atomic_store(canary1 + t*16 + gw, (unsigned)(t+1), __ATOMIC_RELAXED, __HIP_MEMORY_SCOPE_AGENT);
    }
  }
}

// ---- final reduce: cost = mean(log(S) - LT)
__global__ void k_reduce(const float* __restrict__ S, const float* __restrict__ LT,
                         float* __restrict__ out){
  __shared__ float red[256];
  float s = 0.f;
  for (int r = threadIdx.x; r < 8192; r += 256) s += __logf(S[r]) - LT[r];
  red[threadIdx.x] = s;
  __syncthreads();
  for (int st = 128; st > 0; st >>= 1){
    if (threadIdx.x < st) red[threadIdx.x] += red[threadIdx.x + st];
    __syncthreads();
  }
  if (threadIdx.x == 0) out[0] = red[0] / 8192.0f;
}

extern "C" void kernel_launch(void* const* d_in, const int* in_sizes, int n_in,
                              void* d_out, int out_size, void* d_ws, size_t ws_size,
                              hipStream_t stream){
  const int*   input   = (const int*)  d_in[0];
  const int*   targets = (const int*)  d_in[1];
  const float* emb     = (const float*)d_in[2];
  const float* W0      = (const float*)d_in[3];
  const float* b0      = (const float*)d_in[4];
  const float* W1      = (const float*)d_in[5];
  const float* b1      = (const float*)d_in[6];
  const float* Wsm     = (const float*)d_in[7];
  const float* sb      = (const float*)d_in[8];

  char* ws = (char*)d_ws;
  size_t off = 0;
  auto alloc = [&](size_t bytes)->char*{
    char* p = ws + off; off += (bytes + 255) & ~(size_t)255; return p;
  };
  unsigned short* Xbf  = (unsigned short*)alloc(8192ull*256*2);
  unsigned short* W0xT = (unsigned short*)alloc(1024ull*256*2);
  unsigned short* W0hT = (unsigned short*)alloc(1024ull*256*2);
  unsigned short* W1T  = (unsigned short*)alloc(1024ull*512*2);
  unsigned short* WsT  = (unsigned short*)alloc(16000ull*256*2);
  float*          Z0x  = (float*)         alloc(8192ull*1024*4);
  unsigned short* h0h  = (unsigned short*)alloc(128ull*2048*16);  // 4 MB history
  unsigned short* h1h  = (unsigned short*)alloc(128ull*2048*16);
  unsigned short* H1bf = (unsigned short*)alloc(8192ull*256*2);
  float*          S    = (float*)         alloc(8192ull*4);
  float*          LT   = (float*)         alloc(8192ull*4);
  unsigned*       canary0 = (unsigned*)   alloc(128*16*4);        // 8 KB
  unsigned*       canary1 = (unsigned*)   alloc(128*16*4);

  hipMemsetAsync(S, 0, 8192ull*4, stream);
  hipMemsetAsync(canary0, 0, 2*128*16*4, stream);   // canary0+canary1 contiguous

  k_gather<<<dim3(8192), dim3(256), 0, stream>>>(input, emb, Xbf);
  k_transpose<<<dim3(32, 8),  dim3(32,8), 0, stream>>>(W0,  W0xT, 256, 1024, 1024, 0);
  k_transpose<<<dim3(32, 8),  dim3(32,8), 0, stream>>>(W0,  W0hT, 256, 1024, 1024, 256);
  k_transpose<<<dim3(32, 16), dim3(32,8), 0, stream>>>(W1,  W1T,  512, 1024, 1024, 0);
  k_transpose<<<dim3(500, 8), dim3(32,8), 0, stream>>>(Wsm, WsT,  256, 16000, 16000, 0);

  // Z0x = X @ W0[:256,:] + b0   (M=8192 r'=(t,b), N=1024, K=256); m-major blocks
  k_gemm<0><<<dim3(64, 8), dim3(256), 0, stream>>>(Xbf, W0xT, Z0x, b0, nullptr, nullptr, nullptr);

  // persistent LSTM (8 WGs cooperative; wave-autonomous canary dataflow)
  void* kargs[] = { (void*)&Z0x, (void*)&W0hT, (void*)&W1T, (void*)&b1,
                    (void*)&h0h, (void*)&h1h, (void*)&H1bf, (void*)&canary0, (void*)&canary1 };
  hipLaunchCooperativeKernel((void*)k_lstm, dim3(8), dim3(256), kargs, 0, stream);

  // fused projection + log-softmax partials (M=8192 r=(b,t), N=16000, K=256); m-major blocks
  k_gemm<1><<<dim3(64, 125), dim3(256), 0, stream>>>(H1bf, WsT, nullptr, sb, targets, S, LT);

  k_reduce<<<dim3(1), dim3(256), 0, stream>>>(S, LT, (float*)d_out);
}